// Round 6
// baseline (8035.983 us; speedup 1.0000x reference)
//
#include <hip/hip_runtime.h>
#include <hip/hip_fp16.h>
#include <cstdint>

#define T_STEPS 1024
#define BATCH   128
#define DIM     256   // D
#define HID     256   // H
#define FF      128   // F
#define CHUNK   16

typedef _Float16 h2 __attribute__((ext_vector_type(2)));

// ws layout:
//   fp16 packed weights (units _Float16):
//     WgxP at 0      : [256/8][1024][8] = 262144 halfs (512 KB)  rows k<256 of Wg
//     WghP at 262144 : [256/8][1024][8] = 262144 halfs (512 KB)  rows k>=256
//     W1P  at 524288 : [4][H/8][F][8]   = 131072 halfs (256 KB)
//     W2P  at 655360 : [4][F/8][H][8]   = 131072 halfs (256 KB)
//   z2 exchange (uint, tag<<16 | fp16): [128 b][4 g][2 p][256 c] at byte 1572864 (1 MB)
#define WGXP_OFF 0
#define WGHP_OFF 262144
#define W1P_OFF  524288
#define W2P_OFF  655360
#define WS_HALFS 786432
#define EX_BYTE_OFF 1572864
#define EX_WORDS    262144
#define WS_SPLIT4_BYTES (EX_BYTE_OFF + EX_WORDS * 4)   // ~2.62 MB

__device__ __forceinline__ float sigmoidf_(float x) {
    return 1.0f / (1.0f + __expf(-x));
}
__device__ __forceinline__ float tanhf_(float x) {
    float e = __expf(2.0f * x);
    return 1.0f - 2.0f / (e + 1.0f);
}
__device__ __forceinline__ float fdot2_(h2 a, h2 b, float c) {
#if __has_builtin(__builtin_amdgcn_fdot2)
    return __builtin_amdgcn_fdot2(a, b, c, false);
#else
    return fmaf((float)a.x, (float)b.x, fmaf((float)a.y, (float)b.y, c));
#endif
}

union U4H { uint4 u; h2 h[4]; };
union HU  { unsigned short u; _Float16 h; };

// ---------------- weight convert + repack (fp32 -> fp16) ----------------
__global__ __launch_bounds__(256)
void convert_kernel(const float* __restrict__ Wg,
                    const float* __restrict__ W1,
                    const float* __restrict__ W2,
                    _Float16* __restrict__ ws)
{
    int i = blockIdx.x * 256 + threadIdx.x;
    if (i < 524288) {
        int k = i >> 10, c = i & 1023;
        if (k < 256) {
            ws[WGXP_OFF + (((size_t)(k >> 3) << 10) + c) * 8 + (k & 7)] = (_Float16)Wg[i];
        } else {
            int k2 = k - 256;
            ws[WGHP_OFF + (((size_t)(k2 >> 3) << 10) + c) * 8 + (k2 & 7)] = (_Float16)Wg[i];
        }
    } else if (i < 655360) {
        int j = i - 524288;           // W1 [4][H][F]
        int g = j >> 15, k = (j >> 7) & 255, f = j & 127;
        ws[W1P_OFF + (((size_t)((g << 5) + (k >> 3)) << 7) + f) * 8 + (k & 7)] = (_Float16)W1[j];
    } else if (i < 786432) {
        int j = i - 655360;           // W2 [4][F][H]
        int g = j >> 15, f = (j >> 8) & 127, h = j & 255;
        ws[W2P_OFF + (((size_t)((g << 4) + (f >> 3)) << 8) + h) * 8 + (f & 7)] = (_Float16)W2[j];
    }
}

__global__ __launch_bounds__(512)
void exinit_kernel(unsigned* __restrict__ ex) {
    int i = blockIdx.x * 512 + threadIdx.x;
    if (i < EX_WORDS) ex[i] = 0u;     // tag 0 != any s+1 >= 1
}

// ---------------- 4-way gate split, dual phase-offset chains per WG ----------------
// blk = g*64 + bp. Chain A = batch bp, chain B = batch bp+64. All 1024 threads work
// on one chain's phase at a time; the other chain's exchange latency hides underneath.
// Exchange: tagged relaxed agent atomics (R5-proven), NO fences.
__global__ __launch_bounds__(1024)
void qlstm_split4x_kernel(const float* __restrict__ x,
                          const _Float16* __restrict__ ws,
                          unsigned* ex,
                          const float* __restrict__ bg,
                          const float* __restrict__ b1,
                          const float* __restrict__ b2,
                          float* __restrict__ out)
{
    const int blk = blockIdx.x;
    const int g   = blk >> 6;          // gate 0..3
    const int bp  = blk & 63;          // batch-pair index
    const int tid = threadIdx.x;
    const int bA  = bp;
    const int bB  = bp + 64;

    __shared__ __align__(16) _Float16 xcA[CHUNK * DIM];     // 8 KB
    __shared__ __align__(16) _Float16 xcB[CHUNK * DIM];     // 8 KB
    __shared__ __align__(16) _Float16 zxcA[CHUNK * 256];    // 8 KB (z x-part + bg)
    __shared__ __align__(16) _Float16 zxcB[CHUNK * 256];    // 8 KB
    __shared__ __align__(16) _Float16 ch2A[256];            // h(t-1), chain A
    __shared__ __align__(16) _Float16 ch2B[256];
    __shared__ __align__(16) _Float16 zh[256];              // z scratch (one chain at a time)
    __shared__ __align__(16) _Float16 h1h[128];             // FFN hidden scratch
    __shared__ float pbuf[8 * 256];                         // split-K partials (8 KB)
    __shared__ float bgs[256], b1s[128], b2s[256];

    if (tid < 256) {
        bgs[tid] = bg[(g << 8) + tid];
        b2s[tid] = b2[(g << 8) + tid];
        ch2A[tid] = (_Float16)0.0f;
        ch2B[tid] = (_Float16)0.0f;
    }
    if (tid < 128) b1s[tid] = b1[(g << 7) + tid];
    __syncthreads();

    float cA = 0.0f, cB = 0.0f;   // cell state, held by threads tid<256 (col = tid)

    const uint4* __restrict__ wgxp = reinterpret_cast<const uint4*>(ws + WGXP_OFF);
    const uint4* __restrict__ wghp = reinterpret_cast<const uint4*>(ws + WGHP_OFF);
    const uint4* __restrict__ w1p  = reinterpret_cast<const uint4*>(ws + W1P_OFF);
    const uint4* __restrict__ w2p  = reinterpret_cast<const uint4*>(ws + W2P_OFF);

    // ---- stage x chunk + x-GEMM for chain X, steps s..s+15 ----
    auto stage_xgemm = [&](int s, _Float16* xcX, _Float16* zxcX, int bX) {
        {
            int idx4 = tid * 4;                 // 4096 x-elements
            int tl = idx4 >> 8, d0 = idx4 & 255;
            float4 v = reinterpret_cast<const float4*>(
                x + ((size_t)(s + tl) * BATCH + bX) * DIM)[d0 >> 2];
            xcX[tl * 256 + d0 + 0] = (_Float16)v.x;
            xcX[tl * 256 + d0 + 1] = (_Float16)v.y;
            xcX[tl * 256 + d0 + 2] = (_Float16)v.z;
            xcX[tl * 256 + d0 + 3] = (_Float16)v.w;
        }
        __syncthreads();
        {
            const int c = tid & 255, tq = tid >> 8;      // tq -> tc = tq*4+j
            const U4H* xcv = reinterpret_cast<const U4H*>(xcX);
            float acc[4];
            #pragma unroll
            for (int j = 0; j < 4; ++j) acc[j] = bgs[c];
            for (int k8 = 0; k8 < 32; ++k8) {
                U4H w; w.u = wgxp[(k8 << 10) + (g << 8) + c];
                #pragma unroll
                for (int j = 0; j < 4; ++j) {
                    U4H xv; xv.u = xcv[(tq * 4 + j) * 32 + k8].u;
                    acc[j] = fdot2_(xv.h[0], w.h[0], acc[j]);
                    acc[j] = fdot2_(xv.h[1], w.h[1], acc[j]);
                    acc[j] = fdot2_(xv.h[2], w.h[2], acc[j]);
                    acc[j] = fdot2_(xv.h[3], w.h[3], acc[j]);
                }
            }
            #pragma unroll
            for (int j = 0; j < 4; ++j)
                zxcX[(tq * 4 + j) * 256 + c] = (_Float16)acc[j];
        }
        __syncthreads();
    };

    // ---- compute one step s for chain X and publish its z2 (tag s+1) ----
    auto compute_publish = [&](int s, _Float16* xcX, _Float16* zxcX,
                               _Float16* ch2X, int bX) {
        if ((s & 15) == 0) stage_xgemm(s, xcX, zxcX, bX);

        // p1: z[c] = zx[c] + sum_k h[k]*Wgh[k][g*256+c]; split-K 4 x 64 rows
        {
            const int c = tid & 255, kh = tid >> 8;
            const h2* hp = reinterpret_cast<const h2*>(ch2X);
            float acc = 0.0f;
            #pragma unroll
            for (int k8 = kh * 8; k8 < kh * 8 + 8; ++k8) {
                U4H w; w.u = wghp[(k8 << 10) + (g << 8) + c];
                acc = fdot2_(hp[4 * k8 + 0], w.h[0], acc);
                acc = fdot2_(hp[4 * k8 + 1], w.h[1], acc);
                acc = fdot2_(hp[4 * k8 + 2], w.h[2], acc);
                acc = fdot2_(hp[4 * k8 + 3], w.h[3], acc);
            }
            pbuf[kh * 256 + c] = acc;
        }
        __syncthreads();
        if (tid < 256) {
            float z = (float)zxcX[(s & 15) * 256 + tid]
                    + pbuf[tid] + pbuf[256 + tid] + pbuf[512 + tid] + pbuf[768 + tid];
            zh[tid] = (_Float16)z;
        }
        __syncthreads();

        // p2: h1[f] = relu(sum_k z[k]*W1[g][k][f] + b1); split-K 8 x 32 rows
        {
            const int f = tid & 127, kq = tid >> 7;
            const h2* zp = reinterpret_cast<const h2*>(zh);
            float acc = 0.0f;
            #pragma unroll
            for (int k8 = kq * 4; k8 < kq * 4 + 4; ++k8) {
                U4H w; w.u = w1p[(((g << 5) + k8) << 7) + f];
                acc = fdot2_(zp[4 * k8 + 0], w.h[0], acc);
                acc = fdot2_(zp[4 * k8 + 1], w.h[1], acc);
                acc = fdot2_(zp[4 * k8 + 2], w.h[2], acc);
                acc = fdot2_(zp[4 * k8 + 3], w.h[3], acc);
            }
            pbuf[kq * 128 + f] = acc;
        }
        __syncthreads();
        if (tid < 128) {
            float v = b1s[tid];
            #pragma unroll
            for (int q = 0; q < 8; ++q) v += pbuf[q * 128 + tid];
            h1h[tid] = (_Float16)fmaxf(v, 0.0f);
        }
        __syncthreads();

        // p3: z2[c] = sum_f h1[f]*W2[g][f][c] + b2; split-F 4 x 32 rows
        {
            const int c = tid & 255, fq = tid >> 8;
            const h2* hp1 = reinterpret_cast<const h2*>(h1h);
            float acc = 0.0f;
            #pragma unroll
            for (int f8 = fq * 4; f8 < fq * 4 + 4; ++f8) {
                U4H w; w.u = w2p[(((g << 4) + f8) << 8) + c];
                acc = fdot2_(hp1[4 * f8 + 0], w.h[0], acc);
                acc = fdot2_(hp1[4 * f8 + 1], w.h[1], acc);
                acc = fdot2_(hp1[4 * f8 + 2], w.h[2], acc);
                acc = fdot2_(hp1[4 * f8 + 3], w.h[3], acc);
            }
            pbuf[fq * 256 + c] = acc;
        }
        __syncthreads();
        if (tid < 256) {
            float z2 = b2s[tid]
                     + pbuf[tid] + pbuf[256 + tid] + pbuf[512 + tid] + pbuf[768 + tid];
            HU hu; hu.h = (_Float16)z2;
            unsigned word = ((unsigned)(s + 1) << 16) | (unsigned)hu.u;
            unsigned idx = (unsigned)(bX * 2048 + g * 512 + ((s & 1) << 8) + tid);
            __hip_atomic_store(&ex[idx], word, __ATOMIC_RELAXED, __HIP_MEMORY_SCOPE_AGENT);
        }
        __syncthreads();   // pbuf reusable
    };

    // ---- wait for all 4 gates' z2 of (X, s), update c/h ----
    auto spin_update = [&](int s, _Float16* ch2X, float& c_reg, int bX) {
        if (tid < 256) {
            const unsigned base = (unsigned)(bX * 2048 + ((s & 1) << 8) + tid);
            const unsigned want = (unsigned)(s + 1) << 16;
            unsigned w0, w1, w2, w3;
            for (;;) {
                w0 = __hip_atomic_load(&ex[base],        __ATOMIC_RELAXED, __HIP_MEMORY_SCOPE_AGENT);
                w1 = __hip_atomic_load(&ex[base + 512],  __ATOMIC_RELAXED, __HIP_MEMORY_SCOPE_AGENT);
                w2 = __hip_atomic_load(&ex[base + 1024], __ATOMIC_RELAXED, __HIP_MEMORY_SCOPE_AGENT);
                w3 = __hip_atomic_load(&ex[base + 1536], __ATOMIC_RELAXED, __HIP_MEMORY_SCOPE_AGENT);
                unsigned m = ((w0 ^ want) | (w1 ^ want) | (w2 ^ want) | (w3 ^ want)) & 0xFFFF0000u;
                if (m == 0u) break;
                __builtin_amdgcn_s_sleep(1);
            }
            HU hf, hi, hg, ho;
            hf.u = (unsigned short)(w0 & 0xFFFFu);
            hi.u = (unsigned short)(w1 & 0xFFFFu);
            hg.u = (unsigned short)(w2 & 0xFFFFu);
            ho.u = (unsigned short)(w3 & 0xFFFFu);
            float fg = sigmoidf_((float)hf.h);
            float ig = sigmoidf_((float)hi.h);
            float gg = tanhf_((float)hg.h);
            float og = sigmoidf_((float)ho.h);
            c_reg = fmaf(fg, c_reg, ig * gg);
            float hh = og * tanhf_(c_reg);
            ch2X[tid] = (_Float16)hh;
            if (g == 0) {
                out[((size_t)s * BATCH + bX) * HID + tid] = hh;
                if (s == T_STEPS - 1) {
                    const size_t TBH = (size_t)T_STEPS * BATCH * HID;
                    out[TBH + (size_t)bX * HID + tid] = hh;
                    out[TBH + (size_t)BATCH * HID + (size_t)bX * HID + tid] = c_reg;
                }
            }
        }
        __syncthreads();
    };

    // prologue: chain A one step ahead in publish order
    compute_publish(0, xcA, zxcA, ch2A, bA);

    for (int t = 0; t < T_STEPS; ++t) {
        compute_publish(t, xcB, zxcB, ch2B, bB);     // B compute hides A's exchange
        spin_update(t, ch2A, cA, bA);
        if (t + 1 < T_STEPS)
            compute_publish(t + 1, xcA, zxcA, ch2A, bA);  // A compute hides B's exchange
        spin_update(t, ch2B, cB, bB);
    }
}

// ---------------- fallback: R4 chunk kernel (one WG per batch element) ----------------
__global__ __launch_bounds__(1024)
void qlstm_chunk_kernel(const float* __restrict__ x,
                        const _Float16* __restrict__ ws,
                        const float* __restrict__ bg,
                        const float* __restrict__ b1,
                        const float* __restrict__ b2,
                        float* __restrict__ out)
{
    const int b   = blockIdx.x;
    const int tid = threadIdx.x;

    __shared__ __align__(16) _Float16 xc[CHUNK * DIM];
    __shared__ __align__(16) _Float16 zxc[CHUNK * 1024];
    __shared__ __align__(16) _Float16 zh[1024];
    __shared__ __align__(16) _Float16 h1h[512];
    __shared__ __align__(16) _Float16 ch2buf[HID];
    __shared__ float z2buf[1024];
    __shared__ float cbuf[HID];
    __shared__ float hbuf[HID];

    const float rbg = bg[tid];
    const float rb1 = (tid < 512) ? b1[tid] : 0.0f;
    const float rb2 = b2[tid];

    if (tid < HID) { cbuf[tid] = 0.0f; hbuf[tid] = 0.0f; ch2buf[tid] = (_Float16)0.0f; }

    const uint4* __restrict__ wgxp = reinterpret_cast<const uint4*>(ws + WGXP_OFF);
    const uint4* __restrict__ wghp = reinterpret_cast<const uint4*>(ws + WGHP_OFF);
    const uint4* __restrict__ w1p  = reinterpret_cast<const uint4*>(ws + W1P_OFF);
    const uint4* __restrict__ w2p  = reinterpret_cast<const uint4*>(ws + W2P_OFF);
    const h2* ch2 = reinterpret_cast<const h2*>(ch2buf);
    const U4H* xcv = reinterpret_cast<const U4H*>(xc);

    for (int t0 = 0; t0 < T_STEPS; t0 += CHUNK) {
        #pragma unroll
        for (int j = 0; j < (CHUNK * DIM) / 1024; ++j) {
            int idx = tid + j * 1024;
            int tl = idx >> 8, d = idx & 255;
            xc[tl * DIM + d] = (_Float16)x[((size_t)(t0 + tl) * BATCH + b) * DIM + d];
        }
        __syncthreads();

        {
            float acc[CHUNK];
            #pragma unroll
            for (int tc = 0; tc < CHUNK; ++tc) acc[tc] = rbg;
            for (int k8 = 0; k8 < DIM / 8; ++k8) {
                U4H w; w.u = wgxp[(k8 << 10) + tid];
                #pragma unroll
                for (int tc = 0; tc < CHUNK; ++tc) {
                    U4H xv; xv.u = xcv[tc * (DIM / 8) + k8].u;
                    acc[tc] = fdot2_(xv.h[0], w.h[0], acc[tc]);
                    acc[tc] = fdot2_(xv.h[1], w.h[1], acc[tc]);
                    acc[tc] = fdot2_(xv.h[2], w.h[2], acc[tc]);
                    acc[tc] = fdot2_(xv.h[3], w.h[3], acc[tc]);
                }
            }
            #pragma unroll
            for (int tc = 0; tc < CHUNK; ++tc) zxc[tc * 1024 + tid] = (_Float16)acc[tc];
        }
        __syncthreads();

        for (int tc = 0; tc < CHUNK; ++tc) {
            {
                float acc = (float)zxc[tc * 1024 + tid];
                #pragma unroll 8
                for (int k8 = 0; k8 < HID / 8; ++k8) {
                    U4H w; w.u = wghp[(k8 << 10) + tid];
                    acc = fdot2_(ch2[4 * k8 + 0], w.h[0], acc);
                    acc = fdot2_(ch2[4 * k8 + 1], w.h[1], acc);
                    acc = fdot2_(ch2[4 * k8 + 2], w.h[2], acc);
                    acc = fdot2_(ch2[4 * k8 + 3], w.h[3], acc);
                }
                zh[tid] = (_Float16)acc;
            }
            __syncthreads();

            if (tid < 512) {
                const int g = tid >> 7, f = tid & 127;
                const h2* zp = reinterpret_cast<const h2*>(zh + (g << 8));
                float acc = rb1;
                #pragma unroll 8
                for (int k8 = 0; k8 < HID / 8; ++k8) {
                    U4H w; w.u = w1p[(((g << 5) + k8) << 7) + f];
                    acc = fdot2_(zp[4 * k8 + 0], w.h[0], acc);
                    acc = fdot2_(zp[4 * k8 + 1], w.h[1], acc);
                    acc = fdot2_(zp[4 * k8 + 2], w.h[2], acc);
                    acc = fdot2_(zp[4 * k8 + 3], w.h[3], acc);
                }
                h1h[tid] = (_Float16)fmaxf(acc, 0.0f);
            }
            __syncthreads();

            {
                const int g = tid >> 8, hcol = tid & 255;
                const h2* hp = reinterpret_cast<const h2*>(h1h + (g << 7));
                float acc = rb2;
                #pragma unroll 8
                for (int f8 = 0; f8 < FF / 8; ++f8) {
                    U4H w; w.u = w2p[(((g << 4) + f8) << 8) + hcol];
                    acc = fdot2_(hp[4 * f8 + 0], w.h[0], acc);
                    acc = fdot2_(hp[4 * f8 + 1], w.h[1], acc);
                    acc = fdot2_(hp[4 * f8 + 2], w.h[2], acc);
                    acc = fdot2_(hp[4 * f8 + 3], w.h[3], acc);
                }
                z2buf[tid] = acc;
            }
            __syncthreads();

            if (tid < HID) {
                float zf = z2buf[tid];
                float zi = z2buf[HID + tid];
                float zg = z2buf[2 * HID + tid];
                float zo = z2buf[3 * HID + tid];
                float fg = sigmoidf_(zf);
                float ig = sigmoidf_(zi);
                float gg = tanhf_(zg);
                float og = sigmoidf_(zo);
                float cc = fmaf(fg, cbuf[tid], ig * gg);
                float hh = og * tanhf_(cc);
                cbuf[tid] = cc;
                hbuf[tid] = hh;
                ch2buf[tid] = (_Float16)hh;
                out[((size_t)(t0 + tc) * BATCH + b) * HID + tid] = hh;
            }
            __syncthreads();
        }
    }

    if (tid < HID) {
        const size_t TBH = (size_t)T_STEPS * BATCH * HID;
        out[TBH + (size_t)b * HID + tid] = hbuf[tid];
        out[TBH + (size_t)BATCH * HID + (size_t)b * HID + tid] = cbuf[tid];
    }
}

extern "C" void kernel_launch(void* const* d_in, const int* in_sizes, int n_in,
                              void* d_out, int out_size, void* d_ws, size_t ws_size,
                              hipStream_t stream) {
    const float* x  = (const float*)d_in[0];
    const float* Wg = (const float*)d_in[1];
    const float* bg = (const float*)d_in[2];
    const float* b1 = (const float*)d_in[4];
    const float* W1 = (const float*)d_in[3];
    const float* W2 = (const float*)d_in[5];
    const float* b2 = (const float*)d_in[6];
    float* out = (float*)d_out;
    char* wsc = (char*)d_ws;

    if (ws_size >= (size_t)WS_SPLIT4_BYTES) {
        _Float16* ws = (_Float16*)wsc;
        unsigned* ex = (unsigned*)(wsc + EX_BYTE_OFF);
        convert_kernel<<<WS_HALFS / 256, 256, 0, stream>>>(Wg, W1, W2, ws);
        exinit_kernel<<<EX_WORDS / 512, 512, 0, stream>>>(ex);
        qlstm_split4x_kernel<<<256, 1024, 0, stream>>>(x, ws, ex, bg, b1, b2, out);
    } else if (ws_size >= (size_t)WS_HALFS * sizeof(_Float16)) {
        _Float16* ws = (_Float16*)wsc;
        convert_kernel<<<WS_HALFS / 256, 256, 0, stream>>>(Wg, W1, W2, ws);
        qlstm_chunk_kernel<<<BATCH, 1024, 0, stream>>>(x, ws, bg, b1, b2, out);
    }
}